// Round 13
// baseline (591.461 us; speedup 1.0000x reference)
//
#include <hip/hip_runtime.h>

// ---------------- problem constants ----------------
#define B_ 4
#define N_ 96
#define C_ 256
#define NPAIR (B_*N_*N_)        // 36864 pair rows
#define CE (NPAIR*C_)           // 9437184 elements per qkv slab
#define SCALE 8.838834764831844f  // 50/sqrt(32)
#define CP 132                  // gemm epilogue LDS pitch (conflict-free)
// ws budget: 256 MiB. Usage ~229 MB.
// Round-26: gemm __launch_bounds__(256,4). VGPR_Count 76 EXCLUDES the 64-AGPR
// accumulator -> 140 total regs = 3 waves/SIMD static cap (37.5%); measured
// 23% is that cap minus ramp/tail. LDS (4 blk) never was the binder -- which
// explains the R4-R7 tile-sweep null results. Forcing 4 waves/SIMD (128-reg
// budget) needs the compiler to shave 12 VGPRs; spill = revert trigger.
// Rest identical to R12 (579.4us; best-family config).

typedef __attribute__((ext_vector_type(4))) float f32x4;
typedef __attribute__((ext_vector_type(8))) __bf16 bf16x8;
typedef __attribute__((ext_vector_type(4))) __bf16 bf16x4;
typedef __attribute__((ext_vector_type(4))) unsigned short u16x4;
typedef __attribute__((ext_vector_type(8))) unsigned short u16x8;

__device__ __forceinline__ unsigned short f2bf(float f){
  __bf16 h = (__bf16)f;                      // RNE convert
  return __builtin_bit_cast(unsigned short, h);
}
__device__ __forceinline__ float bf2f(unsigned short u){
  union { unsigned int i; float f; } v; v.i = ((unsigned int)u) << 16; return v.f;
}

// async global->LDS, 16B per lane; lds dest = wave-uniform base + lane*16
__device__ __forceinline__ void gload16(const void* g, void* l){
  __builtin_amdgcn_global_load_lds((const __attribute__((address_space(1))) unsigned int*)g,
                                   (__attribute__((address_space(3))) unsigned int*)l,
                                   16, 0, 0);
}

// ---------------- K_init: zero stats partials (512 f) + pool acc (1024 f) ----------------
__global__ __launch_bounds__(256) void k_init(float* __restrict__ z){
  for (int i = threadIdx.x; i < 1536; i += 256) z[i] = 0.f;
}

// ---------------- K0: xb = bf16(emb[adj]) + stats partials (fp32-accurate) ----------------
__global__ __launch_bounds__(256) void k_gather(const int* __restrict__ adj,
                                                const float* __restrict__ emb,
                                                unsigned short* __restrict__ xb,
                                                float2* __restrict__ part){
  int tid = threadIdx.x;
  int lp = tid >> 4, lane16 = tid & 15;
  int pair = blockIdx.x*16 + lp;
  int row = adj[pair];
  const f32x4* src = (const f32x4*)(emb + (size_t)row*C_);
  u16x4*       dst = (u16x4*)(xb + (size_t)pair*C_);
  float s = 0.f, q = 0.f;
  for (int v = 0; v < 4; ++v){
    f32x4 t = src[v*16 + lane16];
    u16x4 o;
    o.x = f2bf(t.x); o.y = f2bf(t.y); o.z = f2bf(t.z); o.w = f2bf(t.w);
    dst[v*16 + lane16] = o;
    s += t.x + t.y + t.z + t.w;
    q += t.x*t.x + t.y*t.y + t.z*t.z + t.w*t.w;
  }
  __shared__ float rs[256], rq[256];
  rs[tid] = s; rq[tid] = q; __syncthreads();
  for (int o = 128; o > 0; o >>= 1){
    if (tid < o){ rs[tid] += rs[tid+o]; rq[tid] += rq[tid+o]; }
    __syncthreads();
  }
  if (tid == 0){
    float* pp = (float*)&part[blockIdx.x & 63];
    atomicAdd(pp, rs[0]); atomicAdd(pp+1, rq[0]);
  }
}

// ---------------- K0b: weights fp32->bf16 + per-row fp32 sums (for norm folding) ----------------
__global__ __launch_bounds__(256) void k_wconv(const float* __restrict__ w,
                                               unsigned short* __restrict__ wb,
                                               float* __restrict__ wsum){
  int row  = blockIdx.x*4 + (threadIdx.x >> 6);
  int lane = threadIdx.x & 63;
  f32x4 v = ((const f32x4*)(w + (size_t)row*256))[lane];
  u16x4 o;
  o.x = f2bf(v.x); o.y = f2bf(v.y); o.z = f2bf(v.z); o.w = f2bf(v.w);
  ((u16x4*)(wb + (size_t)row*256))[lane] = o;
  float s = v.x + v.y + v.z + v.w;
  for (int m = 32; m > 0; m >>= 1) s += __shfl_down(s, m);
  if (lane == 0) wsum[row] = s;
}

// ---------------- K4: qkv GEMM, XCD-swizzled grid, folded norm, LDS-staged epilogue ----------------
__global__ __launch_bounds__(256, 4) void k_gemm(const unsigned short* __restrict__ Xb,
                                                 const unsigned short* __restrict__ W,
                                                 const float* __restrict__ wsum_l,
                                                 const float2* __restrict__ part,
                                                 unsigned short* __restrict__ qkv5){
  __shared__ unsigned short smem[128*CP];    // As|Bs carved during K-loop
  unsigned short* As = smem;
  unsigned short* Bs = smem + 128*64;
  const int tid = threadIdx.x;
  const int w = tid >> 6, lane = tid & 63;
  const int quad = lane >> 4, l16 = lane & 15;
  const int L = blockIdx.x;
  const int xcd = L & 7, rest = L >> 3;
  const int nt = rest % 10, kt2 = rest / 10;
  const int m0 = (xcd + 8*kt2) * 128, n0 = nt * 128;
  const int mw = (w & 1) * 64, nw = (w >> 1) * 64;
  // stats: 64-lane shuffle reduction over part[64] (double precision)
  float2 pp = part[lane];
  double S = (double)pp.x, Q = (double)pp.y;
  #pragma unroll
  for (int m = 32; m > 0; m >>= 1){ S += __shfl_xor(S, m); Q += __shfl_xor(Q, m); }
  const float mean = (float)(S / (double)CE);
  const float rstd = (float)(1.0 / sqrt((Q - S*S/(double)CE) / (double)(CE - 1)));
  f32x4 acc[4][4] = {};

  for (int kt = 0; kt < 256; kt += 64){
    const int rbase = w * 32;
    const int rowoff = lane >> 3;
    const int kg = (lane & 7) ^ rowoff;
    for (int i8 = 0; i8 < 4; ++i8){
      int row = rbase + i8*8 + rowoff;
      gload16(Xb + (size_t)(m0+row)*256 + kt + kg*8, &As[(rbase + i8*8)*64]);
      gload16(W  + (size_t)(n0+row)*256 + kt + kg*8, &Bs[(rbase + i8*8)*64]);
    }
    __syncthreads();
    for (int ks = 0; ks < 2; ++ks){
      bf16x8 af[4], bf[4];
      for (int t4 = 0; t4 < 4; ++t4){
        int rm = mw + t4*16 + l16;
        af[t4] = *(const bf16x8*)((const char*)As + rm*128 + ((((ks<<2)|quad) ^ (rm&7))*16));
        int rn = nw + t4*16 + l16;
        bf[t4] = *(const bf16x8*)((const char*)Bs + rn*128 + ((((ks<<2)|quad) ^ (rn&7))*16));
      }
      for (int mi = 0; mi < 4; ++mi)
        for (int ni = 0; ni < 4; ++ni)
          acc[mi][ni] = __builtin_amdgcn_mfma_f32_16x16x32_bf16(af[mi], bf[ni], acc[mi][ni], 0, 0, 0);
    }
    __syncthreads();
  }

  float ws[4];
  #pragma unroll
  for (int ni = 0; ni < 4; ++ni) ws[ni] = wsum_l[n0 + nw + ni*16 + l16];
  for (int mi = 0; mi < 4; ++mi)
    for (int ni = 0; ni < 4; ++ni)
      for (int r = 0; r < 4; ++r){
        int row = mw + mi*16 + quad*4 + r;
        int col = nw + ni*16 + l16;
        float val = rstd*(acc[mi][ni][r] - mean*ws[ni]);
        smem[row*CP + col] = f2bf(val);
      }
  __syncthreads();

  const int t_slab = n0 >> 8;
  const int hbase  = (n0 >> 5) & 7;
  const bool tr = (t_slab == 2) || (t_slab == 4);   // k2/v2: store [bh][j][i][d]
  unsigned short* slab = qkv5 + (size_t)t_slab*CE;
  const int trow = tid >> 4;
  const int tcol = (tid & 15) * 8;
  const int h  = hbase + (tcol >> 5);
  const int dd = tcol & 31;
  for (int pass = 0; pass < 8; ++pass){
    int row = pass*16 + trow;
    int gm = m0 + row;
    int b = gm / 9216; int rem = gm - b*9216;
    int ii = rem / 96, jj = rem - (rem/96)*96;
    int r0 = tr ? jj : ii, c0 = tr ? ii : jj;
    u16x8 vv = *(const u16x8*)&smem[row*CP + tcol];
    *(u16x8*)&slab[(((size_t)(b*8+h)*96 + r0)*96 + c0)*32 + dd] = vv;
  }
}

// ---------------- K5: branch-1 scores; s1 layout [bh][j][i][p] (fp16) ----------------
// Default blockIdx mapping. Non-swapped MFMA, 32B-contiguous stores.
__global__ __launch_bounds__(256) void k_scores1(const unsigned short* __restrict__ qkv5,
                                                 unsigned short* __restrict__ s1){
  __shared__ unsigned short Qs[96*40], Ks[96*40];
  int wg = blockIdx.x; int bh = wg/96, ic = wg - bh*96;   // ic = i
  int tid = threadIdx.x;
  size_t gslab = (size_t)wg*3072;
  const unsigned short* qp = qkv5 + 0*(size_t)CE + gslab;
  const unsigned short* kp = qkv5 + 1*(size_t)CE + gslab;
  for (int g = tid; g < 384; g += 256){
    int j = g >> 2, d8 = (g & 3)*8;
    *(u16x8*)&Qs[j*40 + d8] = *(const u16x8*)&qp[j*32 + d8];
    *(u16x8*)&Ks[j*40 + d8] = *(const u16x8*)&kp[j*32 + d8];
  }
  __syncthreads();
  int w = tid >> 6, lane = tid & 63, quad = lane >> 4, l16 = lane & 15;
  unsigned short* s1o = s1 + (size_t)bh*96*9216;          // [j][i][p]
  #pragma unroll
  for (int r = 0; r < 9; ++r){
    int tile = w*9 + r; int jt = tile/6, pt = tile - jt*6;
    bf16x8 a = *(const bf16x8*)((const char*)Qs + (jt*16 + l16)*80 + quad*16);
    bf16x8 b = *(const bf16x8*)((const char*)Ks + (pt*16 + l16)*80 + quad*16);
    f32x4 cc = {0.f,0.f,0.f,0.f};
    cc = __builtin_amdgcn_mfma_f32_16x16x32_bf16(a, b, cc, 0, 0, 0);  // C[j][p]
    int col = pt*16 + l16;
    #pragma unroll
    for (int rr = 0; rr < 4; ++rr){
      int row = jt*16 + quad*4 + rr;                      // j
      _Float16 hv = (_Float16)(cc[rr] * SCALE);
      s1o[(size_t)row*9216 + ic*96 + col] = __builtin_bit_cast(unsigned short, hv);
    }
  }
}

// ---------------- K6: branch-2 scores + register softmax + O2, per (bh, jj) ----------------
// Swapped QK (C=[p][i]); k2/v2 [bh][j][i][d]: staging is one contiguous
// 6KB run per tensor. Probs in Sh[i][p] pitch 100. LDS 27136 B.
__global__ __launch_bounds__(256) void k_attn2(const unsigned short* __restrict__ qkv5,
                                               const unsigned short* __restrict__ s1,
                                               unsigned short* __restrict__ a_out,
                                               unsigned short* __restrict__ xb,
                                               float* __restrict__ poolAcc,
                                               int last){
  __shared__ unsigned short Sh[96*100];      // phase1: Qs@[0,7680)B, Ks@[7680,15360)B; phase2: probs pitch 100
  __shared__ unsigned short VdM[32*100];     // V2 transposed, pitch 100
  __shared__ float Mx[192], Sx[192];
  float* poolL = Mx;                         // alias: Mx last read pre-sync-C; pool adds post-sync-D
  const int L = blockIdx.x;
  const int virt = (L & 7)*384 + (L >> 3);   // XCD k <- virt in [384k, 384k+384)
  int bh = virt/96, jj = virt - bh*96;
  int b = bh >> 3, h = bh & 7;
  int tid = threadIdx.x;
  int w = tid >> 6, lane = tid & 63, quad = lane >> 4, l16 = lane & 15;
  const unsigned short* qn  = qkv5 + 0*(size_t)CE;
  const unsigned short* k2n = qkv5 + 2*(size_t)CE;
  const unsigned short* v2n = qkv5 + 4*(size_t)CE;
  // prefetch s1 bias: lane needs [i = it*16+l16][p = pt*16+quad*4 ..+3] (8B contiguous)
  const unsigned short* s1g = s1 + ((size_t)bh*96 + jj)*9216;   // [i][p]
  u16x4 s1v[9];
  #pragma unroll
  for (int r = 0; r < 9; ++r){
    int tile = w*9 + r; int it = tile/6, pt = tile - it*6;
    s1v[r] = *(const u16x4*)&s1g[(size_t)(it*16 + l16)*96 + pt*16 + quad*4];
  }
  if (tid < 192){ Mx[tid] = -1e30f; Sx[tid] = 0.f; }   // unwritten slots need identities
  // stage Q (strided) / K2 (contiguous 6KB: [bh][jj][p][d])
  const unsigned short* k2g = k2n + ((size_t)bh*96 + jj)*3072;
  for (int g = tid; g < 384; g += 256){
    int d8 = (g & 3)*8, p = g >> 2;
    size_t base = (((size_t)bh*96 + p)*96 + jj)*32 + d8;
    *(u16x8*)&Sh[p*40 + d8]        = *(const u16x8*)&qn[base];
    *(u16x8*)&Sh[3840 + p*40 + d8] = *(const u16x8*)&k2g[p*32 + d8];
  }
  __syncthreads();                            // sync A
  const bool odd = (w & 1);
  const int itA = (w*9)/6, itB = itA + 1;
  const int slot = w & 1;
  f32x4 sc[9];
  float pmA = -1e30f, pmB = -1e30f;
  #pragma unroll
  for (int r = 0; r < 9; ++r){
    int tile = w*9 + r; int it = tile/6, pt = tile - it*6;
    bf16x8 a  = *(const bf16x8*)((const char*)Sh + 7680 + (pt*16 + l16)*80 + quad*16);  // K2 rows=p
    bf16x8 bb = *(const bf16x8*)((const char*)Sh + (it*16 + l16)*80 + quad*16);          // Q rows=i
    f32x4 cc = {0.f,0.f,0.f,0.f};
    cc = __builtin_amdgcn_mfma_f32_16x16x32_bf16(a, bb, cc, 0, 0, 0);  // C[p][i]
    #pragma unroll
    for (int rr = 0; rr < 4; ++rr){
      _Float16 hv = __builtin_bit_cast(_Float16, (unsigned short)s1v[r][rr]);
      sc[r][rr] = cc[rr]*SCALE + (float)hv;
    }
    float t0 = fmaxf(fmaxf(sc[r][0], sc[r][1]), fmaxf(sc[r][2], sc[r][3]));
    bool inA = odd ? (r < 3) : (r < 6);
    if (inA) pmA = fmaxf(pmA, t0); else pmB = fmaxf(pmB, t0);
  }
  // cross-quad combine (lanes l16, +16, +32, +48 share column i)
  pmA = fmaxf(pmA, __shfl_xor(pmA, 16)); pmA = fmaxf(pmA, __shfl_xor(pmA, 32));
  pmB = fmaxf(pmB, __shfl_xor(pmB, 16)); pmB = fmaxf(pmB, __shfl_xor(pmB, 32));
  if (quad == 0){
    Mx[(itA*16 + l16)*2 + slot] = pmA;
    Mx[(itB*16 + l16)*2 + slot] = pmB;
  }
  __syncthreads();                            // sync B: Qs/Ks reads + Mx writes complete
  // late V2 stage (contiguous source; own LDS region; overlaps softmax below)
  const unsigned short* v2g = v2n + ((size_t)bh*96 + jj)*3072;
  for (int g = tid; g < 384; g += 256){
    int d8 = (g & 3)*8, p = g >> 2;
    u16x8 v = *(const u16x8*)&v2g[p*32 + d8];
    #pragma unroll
    for (int k = 0; k < 8; ++k) VdM[(d8+k)*100 + p] = v[k];
  }
  float2 ta = *(const float2*)&Mx[(itA*16 + l16)*2];
  float2 tb = *(const float2*)&Mx[(itB*16 + l16)*2];
  float mAv = fmaxf(ta.x, ta.y), mBv = fmaxf(tb.x, tb.y);
  float sAa = 0.f, sBa = 0.f;
  #pragma unroll
  for (int r = 0; r < 9; ++r){
    bool inA = odd ? (r < 3) : (r < 6);
    float m = inA ? mAv : mBv;
    #pragma unroll
    for (int rr = 0; rr < 4; ++rr){
      float e = __expf(sc[r][rr] - m);
      sc[r][rr] = e;
      if (inA) sAa += e; else sBa += e;
    }
  }
  sAa += __shfl_xor(sAa, 16); sAa += __shfl_xor(sAa, 32);
  sBa += __shfl_xor(sBa, 16); sBa += __shfl_xor(sBa, 32);
  if (quad == 0){
    Sx[(itA*16 + l16)*2 + slot] = sAa;
    Sx[(itB*16 + l16)*2 + slot] = sBa;
  }
  __syncthreads();                            // sync C: Mx reads + Vd writes + Sx writes fenced
  if (last && tid < 32) poolL[tid] = 0.f;     // Mx region dead from here on
  float2 sa = *(const float2*)&Sx[(itA*16 + l16)*2];
  float2 sb = *(const float2*)&Sx[(itB*16 + l16)*2];
  float invA = 1.f/(sa.x + sa.y), invB = 1.f/(sb.x + sb.y);
  // probs into Sh[i][p] (pitch 100), overwriting dead Qs/Ks; u16x4 per tile
  #pragma unroll
  for (int r = 0; r < 9; ++r){
    int tile = w*9 + r; int it = tile/6, pt = tile - it*6;
    bool inA = odd ? (r < 3) : (r < 6);
    float inv = inA ? invA : invB;
    u16x4 o;
    #pragma unroll
    for (int rr = 0; rr < 4; ++rr) o[rr] = f2bf(sc[r][rr] * inv);
    *(u16x4*)&Sh[(it*16 + l16)*100 + pt*16 + quad*4] = o;
  }
  __syncthreads();                            // sync D
  // write probs [bh][i][j=jj][p]: 8B chunks, 24 lanes cover a full 192B row
  unsigned short* ap = a_out + (size_t)bh*96*9216 + (size_t)jj*96;
  for (int g = tid; g < 2304; g += 256){
    int i = g / 24, c4 = g - i*24;
    *(u16x4*)&ap[(size_t)i*9216 + c4*4] = *(const u16x4*)&Sh[i*100 + c4*4];
  }
  // O2 = P(96i x 96p) @ V2(96p x 32d); pitch-100 rows -> per-lane 8B-aligned split reads
  #pragma unroll
  for (int r = 0; r < 3; ++r){
    int tile = w*3 + r; int it = tile >> 1, dt = tile & 1;
    f32x4 cc = {0.f,0.f,0.f,0.f};
    #pragma unroll
    for (int kp3 = 0; kp3 < 3; ++kp3){
      const char* pa = (const char*)Sh + (it*16 + l16)*200 + kp3*64 + quad*16;
      bf16x4 alo = *(const bf16x4*)pa;
      bf16x4 ahi = *(const bf16x4*)(pa + 8);
      bf16x8 a = __builtin_shufflevector(alo, ahi, 0,1,2,3,4,5,6,7);
      const char* vb = (const char*)VdM + (dt*16 + l16)*200 + kp3*64 + quad*16;
      bf16x4 lo = *(const bf16x4*)vb;
      bf16x4 hi = *(const bf16x4*)(vb + 8);
      bf16x8 bbv = __builtin_shufflevector(lo, hi, 0,1,2,3,4,5,6,7);
      cc = __builtin_amdgcn_mfma_f32_16x16x32_bf16(a, bbv, cc, 0, 0, 0);
    }
    int d = dt*16 + l16;
    if (!last){
      #pragma unroll
      for (int rr = 0; rr < 4; ++rr){
        int i = it*16 + quad*4 + rr;
        xb[(((size_t)b*96 + i)*96 + jj)*256 + h*32 + d] = f2bf(cc[rr]);
      }
    } else {
      atomicAdd(&poolL[d], cc[0] + cc[1] + cc[2] + cc[3]);
    }
  }
  if (last){
    __syncthreads();
    if (tid < 32) atomicAdd(&poolAcc[b*256 + h*32 + tid], poolL[tid]);
  }
}

// ---------------- K7: O1 per (bh, ii); last==1: pool O1 only (no xb access) ----------------
// Default blockIdx mapping. xb RMW values prefetched into registers before
// the staging barrier (T14-lite: issue early, use late).
__global__ __launch_bounds__(256) void k_attn1(const unsigned short* __restrict__ a_in,
                                               const unsigned short* __restrict__ qkv5,
                                               unsigned short* __restrict__ xb,
                                               float2* __restrict__ statsPart,
                                               float* __restrict__ poolAcc,
                                               int last){
  __shared__ unsigned short As[96*104], Vd[32*100];
  __shared__ float redW[8];
  __shared__ float poolL[32];
  int wg = blockIdx.x; int bh = wg/96, ii = wg - bh*96;
  int b = bh >> 3, h = bh & 7;
  int tid = threadIdx.x;
  int w = tid >> 6, lane = tid & 63, quad = lane >> 4, l16 = lane & 15;
  if (tid < 32) poolL[tid] = 0.f;
  const unsigned short* vp = qkv5 + 3*(size_t)CE + ((size_t)bh*96 + ii)*3072;
  for (int g = tid; g < 384; g += 256){
    int d8 = (g & 3)*8, p = g >> 2;
    u16x8 v = *(const u16x8*)&vp[p*32 + d8];
    #pragma unroll
    for (int k = 0; k < 8; ++k) Vd[(d8+k)*100 + p] = v[k];
  }
  const unsigned short* ain = a_in + ((size_t)bh*96 + ii)*9216;   // contiguous
  for (int g = tid; g < 1152; g += 256){
    int j = g / 12, cc = g - j*12;
    *(u16x8*)&As[j*104 + cc*8] = *(const u16x8*)&ain[j*96 + cc*8];
  }
  // prefetch old xb values (12 scalars) -- latency hides under staging + MFMA
  const size_t xbase = ((size_t)b*96 + ii)*96*256 + h*32;
  unsigned short oldv[12];
  if (!last){
    #pragma unroll
    for (int r = 0; r < 3; ++r){
      int tile = w*3 + r; int jt = tile >> 1, dt = tile & 1;
      int d = dt*16 + l16;
      #pragma unroll
      for (int rr = 0; rr < 4; ++rr){
        int j = jt*16 + quad*4 + rr;
        oldv[r*4 + rr] = xb[xbase + (size_t)j*256 + d];
      }
    }
  }
  __syncthreads();
  float ls = 0.f, lq = 0.f;
  #pragma unroll
  for (int r = 0; r < 3; ++r){
    int tile = w*3 + r; int jt = tile >> 1, dt = tile & 1;
    f32x4 cc = {0.f,0.f,0.f,0.f};
    #pragma unroll
    for (int kp3 = 0; kp3 < 3; ++kp3){
      bf16x8 a = *(const bf16x8*)((const char*)As + (jt*16 + l16)*208 + kp3*64 + quad*16);
      const char* vb = (const char*)Vd + (dt*16 + l16)*200 + kp3*64 + quad*16;
      bf16x4 lo = *(const bf16x4*)vb;
      bf16x4 hi = *(const bf16x4*)(vb + 8);
      bf16x8 bb = __builtin_shufflevector(lo, hi, 0,1,2,3,4,5,6,7);
      cc = __builtin_amdgcn_mfma_f32_16x16x32_bf16(a, bb, cc, 0, 0, 0);
    }
    int d = dt*16 + l16;
    if (!last){
      #pragma unroll
      for (int rr = 0; rr < 4; ++rr){
        int j = jt*16 + quad*4 + rr;
        size_t xi = xbase + (size_t)j*256 + d;
        float val = bf2f(oldv[r*4 + rr]) + cc[rr];
        xb[xi] = f2bf(val); ls += val; lq += val*val;
      }
    } else {
      atomicAdd(&poolL[d], cc[0] + cc[1] + cc[2] + cc[3]);
    }
  }
  if (!last){
    #pragma unroll
    for (int m = 32; m > 0; m >>= 1){ ls += __shfl_down(ls, m); lq += __shfl_down(lq, m); }
    if (lane == 0){ redW[w] = ls; redW[4+w] = lq; }
    __syncthreads();
    if (tid == 0){
      float S = redW[0]+redW[1]+redW[2]+redW[3];
      float Q = redW[4]+redW[5]+redW[6]+redW[7];
      float* pp = (float*)&statsPart[blockIdx.x & 63];
      atomicAdd(pp, S); atomicAdd(pp+1, Q);
    }
  } else {
    __syncthreads();
    if (tid < 32) atomicAdd(&poolAcc[b*256 + h*32 + tid], poolL[tid]);
  }
}

// ---------------- K9: head ----------------
__global__ __launch_bounds__(256) void k_head(const float* __restrict__ poolAcc,
                                              const float* __restrict__ hw,
                                              const float* __restrict__ hb,
                                              float* __restrict__ out){
  int b = blockIdx.x, t = threadIdx.x;
  __shared__ float xm[256];
  xm[t] = poolAcc[b*256 + t] * (1.0f/9216.0f);
  __syncthreads();
  float o = hb[t];
  for (int cc = 0; cc < 256; ++cc) o += xm[cc] * hw[t*256 + cc];
  out[b*256 + t] = o;
}

// ---------------- launch ----------------
extern "C" void kernel_launch(void* const* d_in, const int* in_sizes, int n_in,
                              void* d_out, int out_size, void* d_ws, size_t ws_size,
                              hipStream_t stream){
  (void)in_sizes; (void)n_in; (void)out_size; (void)ws_size;
  const int*   adj  = (const int*)d_in[0];
  const float* emb  = (const float*)d_in[1];
  const float* qkvw = (const float*)d_in[2];
  const float* hw   = (const float*)d_in[3];
  const float* hb   = (const float*)d_in[4];

  char* p = (char*)d_ws;
  unsigned short* xb   = (unsigned short*)p; p += (size_t)CE*2;            //  18.87 MB
  unsigned short* qkv5 = (unsigned short*)p; p += (size_t)5*CE*2;          //  94.37 MB
  unsigned short* s1   = (unsigned short*)p; p += (size_t)32*96*9216*2;    //  56.62 MB
  unsigned short* aP   = (unsigned short*)p; p += (size_t)32*96*9216*2;    //  56.62 MB
  unsigned short* wbf  = (unsigned short*)p; p += (size_t)4*1280*256*2;    //   2.62 MB
  float*          wsum = (float*)p;          p += (size_t)4*1280*4;        //  20 KB
  float2*         part = (float2*)p;         p += 4*64*sizeof(float2);
  float*          pool = (float*)p;          p += 1024*sizeof(float);

  k_init  <<<dim3(1),     dim3(256), 0, stream>>>((float*)part);
  k_gather<<<dim3(2304),  dim3(256), 0, stream>>>(adj, emb, xb, part);
  k_wconv <<<dim3(1280),  dim3(256), 0, stream>>>(qkvw, wbf, wsum);
  for (int l = 0; l < 4; ++l){
    int last = (l == 3) ? 1 : 0;
    k_gemm   <<<dim3(2880),    dim3(256), 0, stream>>>(xb, wbf + (size_t)l*1280*256,
                                                       wsum + l*1280, part + l*64, qkv5);
    k_scores1<<<dim3(3072),    dim3(256), 0, stream>>>(qkv5, s1);
    k_attn2  <<<dim3(3072),    dim3(256), 0, stream>>>(qkv5, s1, aP, xb, pool, last);
    k_attn1  <<<dim3(3072),    dim3(256), 0, stream>>>(aP, qkv5, xb,
                                                       part + (l+1 < 4 ? (l+1)*64 : 0),
                                                       pool, last);
  }
  k_head<<<dim3(4), dim3(256), 0, stream>>>(pool, hw, hb, (float*)d_out);
}

// Round 14
// 568.587 us; speedup vs baseline: 1.0402x; 1.0402x over previous
//
#include <hip/hip_runtime.h>

// ---------------- problem constants ----------------
#define B_ 4
#define N_ 96
#define C_ 256
#define NPAIR (B_*N_*N_)        // 36864 pair rows
#define CE (NPAIR*C_)           // 9437184 elements per qkv slab
#define SCALE 8.838834764831844f  // 50/sqrt(32)
#define CP 132                  // gemm epilogue LDS pitch (conflict-free)
// ws budget: 256 MiB. Usage ~229 MB.
// Round-27 (FINAL): R6-exact restore -- the all-time best (573.7us).
// Clean-run trend: R6 573.7 -> +k2/v2-transpose 575.8 -> +attn1-prefetch
// 579.4 -> +launch_bounds(256,4) 591.5. None of the post-R6 "neutral keeps"
// ever showed a counter win; cumulative drift +18us. All reverted.
// Config: gemm 128x128/256t single-buffer gload_lds (5 structures tried;
// dbuf raced or lost residency), scores1 R2-form coalesced stores, attn2
// swapped-QK register softmax + original virt swizzle, attn1 wave-shuffle
// stats. Workload is at a latency/launch floor: 17 launches/iter + fixed
// ~44us harness ws-fill; no kernel exceeds ~35% of any single-pipe ceiling.

typedef __attribute__((ext_vector_type(4))) float f32x4;
typedef __attribute__((ext_vector_type(8))) __bf16 bf16x8;
typedef __attribute__((ext_vector_type(4))) __bf16 bf16x4;
typedef __attribute__((ext_vector_type(4))) unsigned short u16x4;
typedef __attribute__((ext_vector_type(8))) unsigned short u16x8;

__device__ __forceinline__ unsigned short f2bf(float f){
  __bf16 h = (__bf16)f;                      // RNE convert
  return __builtin_bit_cast(unsigned short, h);
}
__device__ __forceinline__ float bf2f(unsigned short u){
  union { unsigned int i; float f; } v; v.i = ((unsigned int)u) << 16; return v.f;
}

// async global->LDS, 16B per lane; lds dest = wave-uniform base + lane*16
__device__ __forceinline__ void gload16(const void* g, void* l){
  __builtin_amdgcn_global_load_lds((const __attribute__((address_space(1))) unsigned int*)g,
                                   (__attribute__((address_space(3))) unsigned int*)l,
                                   16, 0, 0);
}

// ---------------- K_init: zero stats partials (512 f) + pool acc (1024 f) ----------------
__global__ __launch_bounds__(256) void k_init(float* __restrict__ z){
  for (int i = threadIdx.x; i < 1536; i += 256) z[i] = 0.f;
}

// ---------------- K0: xb = bf16(emb[adj]) + stats partials (fp32-accurate) ----------------
__global__ __launch_bounds__(256) void k_gather(const int* __restrict__ adj,
                                                const float* __restrict__ emb,
                                                unsigned short* __restrict__ xb,
                                                float2* __restrict__ part){
  int tid = threadIdx.x;
  int lp = tid >> 4, lane16 = tid & 15;
  int pair = blockIdx.x*16 + lp;
  int row = adj[pair];
  const f32x4* src = (const f32x4*)(emb + (size_t)row*C_);
  u16x4*       dst = (u16x4*)(xb + (size_t)pair*C_);
  float s = 0.f, q = 0.f;
  for (int v = 0; v < 4; ++v){
    f32x4 t = src[v*16 + lane16];
    u16x4 o;
    o.x = f2bf(t.x); o.y = f2bf(t.y); o.z = f2bf(t.z); o.w = f2bf(t.w);
    dst[v*16 + lane16] = o;
    s += t.x + t.y + t.z + t.w;
    q += t.x*t.x + t.y*t.y + t.z*t.z + t.w*t.w;
  }
  __shared__ float rs[256], rq[256];
  rs[tid] = s; rq[tid] = q; __syncthreads();
  for (int o = 128; o > 0; o >>= 1){
    if (tid < o){ rs[tid] += rs[tid+o]; rq[tid] += rq[tid+o]; }
    __syncthreads();
  }
  if (tid == 0){
    float* pp = (float*)&part[blockIdx.x & 63];
    atomicAdd(pp, rs[0]); atomicAdd(pp+1, rq[0]);
  }
}

// ---------------- K0b: weights fp32->bf16 + per-row fp32 sums (for norm folding) ----------------
__global__ __launch_bounds__(256) void k_wconv(const float* __restrict__ w,
                                               unsigned short* __restrict__ wb,
                                               float* __restrict__ wsum){
  int row  = blockIdx.x*4 + (threadIdx.x >> 6);
  int lane = threadIdx.x & 63;
  f32x4 v = ((const f32x4*)(w + (size_t)row*256))[lane];
  u16x4 o;
  o.x = f2bf(v.x); o.y = f2bf(v.y); o.z = f2bf(v.z); o.w = f2bf(v.w);
  ((u16x4*)(wb + (size_t)row*256))[lane] = o;
  float s = v.x + v.y + v.z + v.w;
  for (int m = 32; m > 0; m >>= 1) s += __shfl_down(s, m);
  if (lane == 0) wsum[row] = s;
}

// ---------------- K4: qkv GEMM, XCD-swizzled grid, folded norm, LDS-staged epilogue ----------------
__global__ __launch_bounds__(256) void k_gemm(const unsigned short* __restrict__ Xb,
                                              const unsigned short* __restrict__ W,
                                              const float* __restrict__ wsum_l,
                                              const float2* __restrict__ part,
                                              unsigned short* __restrict__ qkv5){
  __shared__ unsigned short smem[128*CP];    // As|Bs carved during K-loop
  unsigned short* As = smem;
  unsigned short* Bs = smem + 128*64;
  const int tid = threadIdx.x;
  const int w = tid >> 6, lane = tid & 63;
  const int quad = lane >> 4, l16 = lane & 15;
  const int L = blockIdx.x;
  const int xcd = L & 7, rest = L >> 3;
  const int nt = rest % 10, kt2 = rest / 10;
  const int m0 = (xcd + 8*kt2) * 128, n0 = nt * 128;
  const int mw = (w & 1) * 64, nw = (w >> 1) * 64;
  // stats: 64-lane shuffle reduction over part[64] (double precision)
  float2 pp = part[lane];
  double S = (double)pp.x, Q = (double)pp.y;
  #pragma unroll
  for (int m = 32; m > 0; m >>= 1){ S += __shfl_xor(S, m); Q += __shfl_xor(Q, m); }
  const float mean = (float)(S / (double)CE);
  const float rstd = (float)(1.0 / sqrt((Q - S*S/(double)CE) / (double)(CE - 1)));
  f32x4 acc[4][4] = {};

  for (int kt = 0; kt < 256; kt += 64){
    const int rbase = w * 32;
    const int rowoff = lane >> 3;
    const int kg = (lane & 7) ^ rowoff;
    for (int i8 = 0; i8 < 4; ++i8){
      int row = rbase + i8*8 + rowoff;
      gload16(Xb + (size_t)(m0+row)*256 + kt + kg*8, &As[(rbase + i8*8)*64]);
      gload16(W  + (size_t)(n0+row)*256 + kt + kg*8, &Bs[(rbase + i8*8)*64]);
    }
    __syncthreads();
    for (int ks = 0; ks < 2; ++ks){
      bf16x8 af[4], bf[4];
      for (int t4 = 0; t4 < 4; ++t4){
        int rm = mw + t4*16 + l16;
        af[t4] = *(const bf16x8*)((const char*)As + rm*128 + ((((ks<<2)|quad) ^ (rm&7))*16));
        int rn = nw + t4*16 + l16;
        bf[t4] = *(const bf16x8*)((const char*)Bs + rn*128 + ((((ks<<2)|quad) ^ (rn&7))*16));
      }
      for (int mi = 0; mi < 4; ++mi)
        for (int ni = 0; ni < 4; ++ni)
          acc[mi][ni] = __builtin_amdgcn_mfma_f32_16x16x32_bf16(af[mi], bf[ni], acc[mi][ni], 0, 0, 0);
    }
    __syncthreads();
  }

  float ws[4];
  #pragma unroll
  for (int ni = 0; ni < 4; ++ni) ws[ni] = wsum_l[n0 + nw + ni*16 + l16];
  for (int mi = 0; mi < 4; ++mi)
    for (int ni = 0; ni < 4; ++ni)
      for (int r = 0; r < 4; ++r){
        int row = mw + mi*16 + quad*4 + r;
        int col = nw + ni*16 + l16;
        float val = rstd*(acc[mi][ni][r] - mean*ws[ni]);
        smem[row*CP + col] = f2bf(val);
      }
  __syncthreads();

  const int t_slab = n0 >> 8;
  const int hbase  = (n0 >> 5) & 7;
  unsigned short* slab = qkv5 + (size_t)t_slab*CE;
  const int trow = tid >> 4;
  const int tcol = (tid & 15) * 8;
  const int h  = hbase + (tcol >> 5);
  const int dd = tcol & 31;
  for (int pass = 0; pass < 8; ++pass){
    int row = pass*16 + trow;
    int gm = m0 + row;
    int b = gm / 9216; int rem = gm - b*9216;
    int ii = rem / 96, jj = rem - (rem/96)*96;
    u16x8 vv = *(const u16x8*)&smem[row*CP + tcol];
    *(u16x8*)&slab[(((size_t)(b*8+h)*96 + ii)*96 + jj)*32 + dd] = vv;
  }
}

// ---------------- K5: branch-1 scores; s1 layout [bh][j][i][p] (fp16) ----------------
// R2 form: non-swapped MFMA, direct fp16 stores (16 lanes = 32B contiguous segments).
__global__ __launch_bounds__(256) void k_scores1(const unsigned short* __restrict__ qkv5,
                                                 unsigned short* __restrict__ s1){
  __shared__ unsigned short Qs[96*40], Ks[96*40];
  int wg = blockIdx.x; int bh = wg/96, ic = wg - bh*96;   // ic = i
  int tid = threadIdx.x;
  size_t gslab = (size_t)wg*3072;
  const unsigned short* qp = qkv5 + 0*(size_t)CE + gslab;
  const unsigned short* kp = qkv5 + 1*(size_t)CE + gslab;
  for (int g = tid; g < 384; g += 256){
    int j = g >> 2, d8 = (g & 3)*8;
    *(u16x8*)&Qs[j*40 + d8] = *(const u16x8*)&qp[j*32 + d8];
    *(u16x8*)&Ks[j*40 + d8] = *(const u16x8*)&kp[j*32 + d8];
  }
  __syncthreads();
  int w = tid >> 6, lane = tid & 63, quad = lane >> 4, l16 = lane & 15;
  unsigned short* s1o = s1 + (size_t)bh*96*9216;          // [j][i][p]
  #pragma unroll
  for (int r = 0; r < 9; ++r){
    int tile = w*9 + r; int jt = tile/6, pt = tile - jt*6;
    bf16x8 a = *(const bf16x8*)((const char*)Qs + (jt*16 + l16)*80 + quad*16);
    bf16x8 b = *(const bf16x8*)((const char*)Ks + (pt*16 + l16)*80 + quad*16);
    f32x4 cc = {0.f,0.f,0.f,0.f};
    cc = __builtin_amdgcn_mfma_f32_16x16x32_bf16(a, b, cc, 0, 0, 0);  // C[j][p]
    int col = pt*16 + l16;
    #pragma unroll
    for (int rr = 0; rr < 4; ++rr){
      int row = jt*16 + quad*4 + rr;                      // j
      _Float16 hv = (_Float16)(cc[rr] * SCALE);
      s1o[(size_t)row*9216 + ic*96 + col] = __builtin_bit_cast(unsigned short, hv);
    }
  }
}

// ---------------- K6: branch-2 scores + register softmax + O2, per (bh, jj) ----------------
// Swapped QK (C=[p][i]): p-reduction in-lane + 2 cross-quad shuffles; s1 bias
// prefetched as u16x4 before the staging barrier. Probs land in Sh[i][p]
// (pitch 100). LDS 27136 B.
__global__ __launch_bounds__(256) void k_attn2(const unsigned short* __restrict__ qkv5,
                                               const unsigned short* __restrict__ s1,
                                               unsigned short* __restrict__ a_out,
                                               unsigned short* __restrict__ xb,
                                               float* __restrict__ poolAcc,
                                               int last){
  __shared__ unsigned short Sh[96*100];      // phase1: Qs@[0,7680)B, Ks@[7680,15360)B; phase2: probs pitch 100
  __shared__ unsigned short VdM[32*100];     // V2 transposed, pitch 100
  __shared__ float Mx[192], Sx[192];
  float* poolL = Mx;                         // alias: Mx last read pre-sync-C; pool adds post-sync-D
  const int L = blockIdx.x;
  const int virt = (L & 7)*384 + (L >> 3);   // XCD k <- virt in [384k, 384k+384)
  int bh = virt/96, jj = virt - bh*96;
  int b = bh >> 3, h = bh & 7;
  int tid = threadIdx.x;
  int w = tid >> 6, lane = tid & 63, quad = lane >> 4, l16 = lane & 15;
  const unsigned short* qn  = qkv5 + 0*(size_t)CE;
  const unsigned short* k2n = qkv5 + 2*(size_t)CE;
  const unsigned short* v2n = qkv5 + 4*(size_t)CE;
  // prefetch s1 bias: lane needs [i = it*16+l16][p = pt*16+quad*4 ..+3] (8B contiguous)
  const unsigned short* s1g = s1 + ((size_t)bh*96 + jj)*9216;   // [i][p]
  u16x4 s1v[9];
  #pragma unroll
  for (int r = 0; r < 9; ++r){
    int tile = w*9 + r; int it = tile/6, pt = tile - it*6;
    s1v[r] = *(const u16x4*)&s1g[(size_t)(it*16 + l16)*96 + pt*16 + quad*4];
  }
  if (tid < 192){ Mx[tid] = -1e30f; Sx[tid] = 0.f; }   // unwritten slots need identities
  // stage Q/K2 (u16x8: 4 consecutive lanes cover one contiguous 64B d-row)
  for (int g = tid; g < 384; g += 256){
    int d8 = (g & 3)*8, p = g >> 2;
    size_t base = (((size_t)bh*96 + p)*96 + jj)*32 + d8;
    *(u16x8*)&Sh[p*40 + d8]        = *(const u16x8*)&qn[base];
    *(u16x8*)&Sh[3840 + p*40 + d8] = *(const u16x8*)&k2n[base];
  }
  __syncthreads();                            // sync A
  const bool odd = (w & 1);
  const int itA = (w*9)/6, itB = itA + 1;
  const int slot = w & 1;
  f32x4 sc[9];
  float pmA = -1e30f, pmB = -1e30f;
  #pragma unroll
  for (int r = 0; r < 9; ++r){
    int tile = w*9 + r; int it = tile/6, pt = tile - it*6;
    bf16x8 a  = *(const bf16x8*)((const char*)Sh + 7680 + (pt*16 + l16)*80 + quad*16);  // K2 rows=p
    bf16x8 bb = *(const bf16x8*)((const char*)Sh + (it*16 + l16)*80 + quad*16);          // Q rows=i
    f32x4 cc = {0.f,0.f,0.f,0.f};
    cc = __builtin_amdgcn_mfma_f32_16x16x32_bf16(a, bb, cc, 0, 0, 0);  // C[p][i]
    #pragma unroll
    for (int rr = 0; rr < 4; ++rr){
      _Float16 hv = __builtin_bit_cast(_Float16, (unsigned short)s1v[r][rr]);
      sc[r][rr] = cc[rr]*SCALE + (float)hv;
    }
    float t0 = fmaxf(fmaxf(sc[r][0], sc[r][1]), fmaxf(sc[r][2], sc[r][3]));
    bool inA = odd ? (r < 3) : (r < 6);
    if (inA) pmA = fmaxf(pmA, t0); else pmB = fmaxf(pmB, t0);
  }
  // cross-quad combine (lanes l16, +16, +32, +48 share column i)
  pmA = fmaxf(pmA, __shfl_xor(pmA, 16)); pmA = fmaxf(pmA, __shfl_xor(pmA, 32));
  pmB = fmaxf(pmB, __shfl_xor(pmB, 16)); pmB = fmaxf(pmB, __shfl_xor(pmB, 32));
  if (quad == 0){
    Mx[(itA*16 + l16)*2 + slot] = pmA;
    Mx[(itB*16 + l16)*2 + slot] = pmB;
  }
  __syncthreads();                            // sync B: Qs/Ks reads + Mx writes complete
  // late V2 stage (own region; overlaps softmax below)
  for (int g = tid; g < 384; g += 256){
    int d8 = (g & 3)*8, p = g >> 2;
    u16x8 v = *(const u16x8*)&v2n[(((size_t)bh*96 + p)*96 + jj)*32 + d8];
    #pragma unroll
    for (int k = 0; k < 8; ++k) VdM[(d8+k)*100 + p] = v[k];
  }
  float2 ta = *(const float2*)&Mx[(itA*16 + l16)*2];
  float2 tb = *(const float2*)&Mx[(itB*16 + l16)*2];
  float mAv = fmaxf(ta.x, ta.y), mBv = fmaxf(tb.x, tb.y);
  float sAa = 0.f, sBa = 0.f;
  #pragma unroll
  for (int r = 0; r < 9; ++r){
    bool inA = odd ? (r < 3) : (r < 6);
    float m = inA ? mAv : mBv;
    #pragma unroll
    for (int rr = 0; rr < 4; ++rr){
      float e = __expf(sc[r][rr] - m);
      sc[r][rr] = e;
      if (inA) sAa += e; else sBa += e;
    }
  }
  sAa += __shfl_xor(sAa, 16); sAa += __shfl_xor(sAa, 32);
  sBa += __shfl_xor(sBa, 16); sBa += __shfl_xor(sBa, 32);
  if (quad == 0){
    Sx[(itA*16 + l16)*2 + slot] = sAa;
    Sx[(itB*16 + l16)*2 + slot] = sBa;
  }
  __syncthreads();                            // sync C: Mx reads + Vd writes + Sx writes fenced
  if (last && tid < 32) poolL[tid] = 0.f;     // Mx region dead from here on
  float2 sa = *(const float2*)&Sx[(itA*16 + l16)*2];
  float2 sb = *(const float2*)&Sx[(itB*16 + l16)*2];
  float invA = 1.f/(sa.x + sa.y), invB = 1.f/(sb.x + sb.y);
  // probs into Sh[i][p] (pitch 100), overwriting dead Qs/Ks; u16x4 per tile
  #pragma unroll
  for (int r = 0; r < 9; ++r){
    int tile = w*9 + r; int it = tile/6, pt = tile - it*6;
    bool inA = odd ? (r < 3) : (r < 6);
    float inv = inA ? invA : invB;
    u16x4 o;
    #pragma unroll
    for (int rr = 0; rr < 4; ++rr) o[rr] = f2bf(sc[r][rr] * inv);
    *(u16x4*)&Sh[(it*16 + l16)*100 + pt*16 + quad*4] = o;
  }
  __syncthreads();                            // sync D
  // write probs [bh][i][j=jj][p]: 8B chunks, 24 lanes cover a full 192B row
  unsigned short* ap = a_out + (size_t)bh*96*9216 + (size_t)jj*96;
  for (int g = tid; g < 2304; g += 256){
    int i = g / 24, c4 = g - i*24;
    *(u16x4*)&ap[(size_t)i*9216 + c4*4] = *(const u16x4*)&Sh[i*100 + c4*4];
  }
  // O2 = P(96i x 96p) @ V2(96p x 32d); pitch-100 rows -> per-lane 8B-aligned split reads
  #pragma unroll
  for (int r = 0; r < 3; ++r){
    int tile = w*3 + r; int it = tile >> 1, dt = tile & 1;
    f32x4 cc = {0.f,0.f,0.f,0.f};
    #pragma unroll
    for (int kp3 = 0; kp3 < 3; ++kp3){
      const char* pa = (const char*)Sh + (it*16 + l16)*200 + kp3*64 + quad*16;
      bf16x4 alo = *(const bf16x4*)pa;
      bf16x4 ahi = *(const bf16x4*)(pa + 8);
      bf16x8 a = __builtin_shufflevector(alo, ahi, 0,1,2,3,4,5,6,7);
      const char* vb = (const char*)VdM + (dt*16 + l16)*200 + kp3*64 + quad*16;
      bf16x4 lo = *(const bf16x4*)vb;
      bf16x4 hi = *(const bf16x4*)(vb + 8);
      bf16x8 bbv = __builtin_shufflevector(lo, hi, 0,1,2,3,4,5,6,7);
      cc = __builtin_amdgcn_mfma_f32_16x16x32_bf16(a, bbv, cc, 0, 0, 0);
    }
    int d = dt*16 + l16;
    if (!last){
      #pragma unroll
      for (int rr = 0; rr < 4; ++rr){
        int i = it*16 + quad*4 + rr;
        xb[(((size_t)b*96 + i)*96 + jj)*256 + h*32 + d] = f2bf(cc[rr]);
      }
    } else {
      atomicAdd(&poolL[d], cc[0] + cc[1] + cc[2] + cc[3]);
    }
  }
  if (last){
    __syncthreads();
    if (tid < 32) atomicAdd(&poolAcc[b*256 + h*32 + tid], poolL[tid]);
  }
}

// ---------------- K7: O1 per (bh, ii); last==1: pool O1 only (no xb access) ----------------
// Wave-shuffle stats reduce.
__global__ __launch_bounds__(256) void k_attn1(const unsigned short* __restrict__ a_in,
                                               const unsigned short* __restrict__ qkv5,
                                               unsigned short* __restrict__ xb,
                                               float2* __restrict__ statsPart,
                                               float* __restrict__ poolAcc,
                                               int last){
  __shared__ unsigned short As[96*104], Vd[32*100];
  __shared__ float redW[8];
  __shared__ float poolL[32];
  int wg = blockIdx.x; int bh = wg/96, ii = wg - bh*96;
  int b = bh >> 3, h = bh & 7;
  int tid = threadIdx.x;
  if (tid < 32) poolL[tid] = 0.f;
  const unsigned short* vp = qkv5 + 3*(size_t)CE + ((size_t)bh*96 + ii)*3072;
  for (int g = tid; g < 384; g += 256){
    int d8 = (g & 3)*8, p = g >> 2;
    u16x8 v = *(const u16x8*)&vp[p*32 + d8];
    #pragma unroll
    for (int k = 0; k < 8; ++k) Vd[(d8+k)*100 + p] = v[k];
  }
  const unsigned short* ain = a_in + ((size_t)bh*96 + ii)*9216;   // contiguous
  for (int g = tid; g < 1152; g += 256){
    int j = g / 12, cc = g - j*12;
    *(u16x8*)&As[j*104 + cc*8] = *(const u16x8*)&ain[j*96 + cc*8];
  }
  __syncthreads();
  int w = tid >> 6, lane = tid & 63, quad = lane >> 4, l16 = lane & 15;
  float ls = 0.f, lq = 0.f;
  #pragma unroll
  for (int r = 0; r < 3; ++r){
    int tile = w*3 + r; int jt = tile >> 1, dt = tile & 1;
    f32x4 cc = {0.f,0.f,0.f,0.f};
    #pragma unroll
    for (int kp3 = 0; kp3 < 3; ++kp3){
      bf16x8 a = *(const bf16x8*)((const char*)As + (jt*16 + l16)*208 + kp3*64 + quad*16);
      const char* vb = (const char*)Vd + (dt*16 + l16)*200 + kp3*64 + quad*16;
      bf16x4 lo = *(const bf16x4*)vb;
      bf16x4 hi = *(const bf16x4*)(vb + 8);
      bf16x8 bb = __builtin_shufflevector(lo, hi, 0,1,2,3,4,5,6,7);
      cc = __builtin_amdgcn_mfma_f32_16x16x32_bf16(a, bb, cc, 0, 0, 0);
    }
    int d = dt*16 + l16;
    if (!last){
      #pragma unroll
      for (int rr = 0; rr < 4; ++rr){
        int j = jt*16 + quad*4 + rr;
        size_t xi = (((size_t)b*96 + ii)*96 + j)*256 + h*32 + d;
        float val = bf2f(xb[xi]) + cc[rr];
        xb[xi] = f2bf(val); ls += val; lq += val*val;
      }
    } else {
      atomicAdd(&poolL[d], cc[0] + cc[1] + cc[2] + cc[3]);
    }
  }
  if (!last){
    #pragma unroll
    for (int m = 32; m > 0; m >>= 1){ ls += __shfl_down(ls, m); lq += __shfl_down(lq, m); }
    if (lane == 0){ redW[w] = ls; redW[4+w] = lq; }
    __syncthreads();
    if (tid == 0){
      float S = redW[0]+redW[1]+redW[2]+redW[3];
      float Q = redW[4]+redW[5]+redW[6]+redW[7];
      float* pp = (float*)&statsPart[blockIdx.x & 63];
      atomicAdd(pp, S); atomicAdd(pp+1, Q);
    }
  } else {
    __syncthreads();
    if (tid < 32) atomicAdd(&poolAcc[b*256 + h*32 + tid], poolL[tid]);
  }
}

// ---------------- K9: head ----------------
__global__ __launch_bounds__(256) void k_head(const float* __restrict__ poolAcc,
                                              const float* __restrict__ hw,
                                              const float* __restrict__ hb,
                                              float* __restrict__ out){
  int b = blockIdx.x, t = threadIdx.x;
  __shared__ float xm[256];
  xm[t] = poolAcc[b*256 + t] * (1.0f/9216.0f);
  __syncthreads();
  float o = hb[t];
  for (int cc = 0; cc < 256; ++cc) o += xm[cc] * hw[t*256 + cc];
  out[b*256 + t] = o;
}

// ---------------- launch ----------------
extern "C" void kernel_launch(void* const* d_in, const int* in_sizes, int n_in,
                              void* d_out, int out_size, void* d_ws, size_t ws_size,
                              hipStream_t stream){
  (void)in_sizes; (void)n_in; (void)out_size; (void)ws_size;
  const int*   adj  = (const int*)d_in[0];
  const float* emb  = (const float*)d_in[1];
  const float* qkvw = (const float*)d_in[2];
  const float* hw   = (const float*)d_in[3];
  const float* hb   = (const float*)d_in[4];

  char* p = (char*)d_ws;
  unsigned short* xb   = (unsigned short*)p; p += (size_t)CE*2;            //  18.87 MB
  unsigned short* qkv5 = (unsigned short*)p; p += (size_t)5*CE*2;          //  94.37 MB
  unsigned short* s1   = (unsigned short*)p; p += (size_t)32*96*9216*2;    //  56.62 MB
  unsigned short* aP   = (unsigned short*)p; p += (size_t)32*96*9216*2;    //  56.62 MB
  unsigned short* wbf  = (unsigned short*)p; p += (size_t)4*1280*256*2;    //   2.62 MB
  float*          wsum = (float*)p;          p += (size_t)4*1280*4;        //  20 KB
  float2*         part = (float2*)p;         p += 4*64*sizeof(float2);
  float*          pool = (float*)p;          p += 1024*sizeof(float);

  k_init  <<<dim3(1),     dim3(256), 0, stream>>>((float*)part);
  k_gather<<<dim3(2304),  dim3(256), 0, stream>>>(adj, emb, xb, part);
  k_wconv <<<dim3(1280),  dim3(256), 0, stream>>>(qkvw, wbf, wsum);
  for (int l = 0; l < 4; ++l){
    int last = (l == 3) ? 1 : 0;
    k_gemm   <<<dim3(2880),    dim3(256), 0, stream>>>(xb, wbf + (size_t)l*1280*256,
                                                       wsum + l*1280, part + l*64, qkv5);
    k_scores1<<<dim3(3072),    dim3(256), 0, stream>>>(qkv5, s1);
    k_attn2  <<<dim3(3072),    dim3(256), 0, stream>>>(qkv5, s1, aP, xb, pool, last);
    k_attn1  <<<dim3(3072),    dim3(256), 0, stream>>>(aP, qkv5, xb,
                                                       part + (l+1 < 4 ? (l+1)*64 : 0),
                                                       pool, last);
  }
  k_head<<<dim3(4), dim3(256), 0, stream>>>(pool, hw, hb, (float*)d_out);
}